// Round 13
// baseline (264.265 us; speedup 1.0000x reference)
//
#include <hip/hip_runtime.h>

typedef __bf16 bf16;
typedef __bf16 bf16x4 __attribute__((ext_vector_type(4)));
typedef __bf16 bf16x8 __attribute__((ext_vector_type(8)));
typedef float f32x4 __attribute__((ext_vector_type(4)));

#define MFMA16(a,b,c) __builtin_amdgcn_mfma_f32_16x16x32_bf16((a),(b),(c),0,0,0)
#define SBAR() __builtin_amdgcn_s_barrier()
#define SCHED0() __builtin_amdgcn_sched_barrier(0)

// Shapes (fixed): B=32, N=384, C=768, H=12, Dh=64, mt=128, 2B=64 batches.
// Global inputs/outputs FLOAT32; intermediates bf16.
// Xb (x bf16 [24576][768]) + Wq (qkv_w bf16 [2304][768]) live in d_out scratch.
// ws: Q | K | VT | ATT (each 36 MB bf16) = 151 MB; Wp reuses Q after attn.
// V stored TRANSPOSED (VT[b'][h][d][tok]) by the qkv epilogue.
//
// r13 (on r12 best=249us): attn softmax critical path.
//  (a) Q scale folds log2(e): 0.125 -> 0.18033688; softmax uses exp2f
//      (v_exp_f32 IS 2^x) -> deletes 64 v_mul/chunk/lane.
//  (b) max & sum reductions as depth-5 trees (were 31-deep serial chains
//      - source order pinned them; ~250cy dep stall per half).
// Everything else byte-identical to r12.

__device__ inline void gload16(const bf16* g, bf16* l) {
  __builtin_amdgcn_global_load_lds(
      (const __attribute__((address_space(1))) void*)g,
      (__attribute__((address_space(3))) void*)l, 16, 0, 0);
}

__device__ inline void stage128(const bf16* __restrict__ gsrc,
                                bf16* lds_base, int tid, int wv) {
#pragma unroll
  for (int r = 0; r < 4; ++r) {
    int s = r * 256 + tid;                        // 0..1023
    int row = s >> 3;
    int chunk = (s & 7) ^ (row & 7);
    gload16(gsrc + (size_t)row * 768 + chunk * 8,
            lds_base + (size_t)(r * 256 + wv * 64) * 8);
  }
}

__device__ inline bf16x8 frag64(const bf16* buf, int row, int ks, int lg) {
  int slot = ((ks << 2) | lg) ^ (row & 7);
  return *(const bf16x8*)(buf + (size_t)row * 64 + slot * 8);
}

// Counted-vmcnt K-loop over NTILES tiles of BK=64 (r8/r9, verified).
#define GEMM128_LOOP(APANEL, BPANEL, NTILES)                                    \
  do {                                                                          \
    stage128((APANEL), &As[0][0][0], tid, wv);                                  \
    stage128((BPANEL), &Bs[0][0][0], tid, wv);                                  \
    stage128((APANEL) + 64, &As[1][0][0], tid, wv);                             \
    stage128((BPANEL) + 64, &Bs[1][0][0], tid, wv);                             \
    asm volatile("s_waitcnt vmcnt(8)" ::: "memory"); SCHED0();                  \
    SBAR();                                                                     \
    int c = 0;                                                                  \
    for (int t = 0; t < (NTILES); ++t) {                                        \
      const bf16* Ab = &As[c][0][0];                                            \
      const bf16* Bb = &Bs[c][0][0];                                            \
      bf16x8 af[4][2], bfr[4][2];                                               \
      _Pragma("unroll")                                                         \
      for (int nf = 0; nf < 4; ++nf)                                            \
        _Pragma("unroll")                                                       \
        for (int ks = 0; ks < 2; ++ks)                                          \
          bfr[nf][ks] = frag64(Bb, wc + nf * 16 + lr, ks, lg);                  \
      _Pragma("unroll")                                                         \
      for (int mf = 0; mf < 4; ++mf)                                            \
        _Pragma("unroll")                                                       \
        for (int ks = 0; ks < 2; ++ks)                                          \
          af[mf][ks] = frag64(Ab, wr + mf * 16 + lr, ks, lg);                   \
      asm volatile("s_waitcnt lgkmcnt(0)" ::: "memory"); SCHED0();              \
      SBAR();   /* all waves done reading buf[c] -> safe to refill */           \
      if (t + 2 < (NTILES)) {                                                   \
        stage128((APANEL) + (t + 2) * 64, &As[c][0][0], tid, wv);               \
        stage128((BPANEL) + (t + 2) * 64, &Bs[c][0][0], tid, wv);               \
      }                                                                         \
      __builtin_amdgcn_s_setprio(1);                                            \
      _Pragma("unroll")                                                         \
      for (int mf = 0; mf < 4; ++mf)                                            \
        _Pragma("unroll")                                                       \
        for (int nf = 0; nf < 4; ++nf)                                          \
          _Pragma("unroll")                                                     \
          for (int ks = 0; ks < 2; ++ks)                                        \
            acc[mf][nf] = MFMA16(af[mf][ks], bfr[nf][ks], acc[mf][nf]);         \
      __builtin_amdgcn_s_setprio(0);                                            \
      if (t + 2 < (NTILES)) { asm volatile("s_waitcnt vmcnt(8)" ::: "memory"); }\
      else                  { asm volatile("s_waitcnt vmcnt(0)" ::: "memory"); }\
      SCHED0();                                                                 \
      SBAR();   /* buf[c^1] (tile t+1) now globally ready */                    \
      c ^= 1;                                                                   \
    }                                                                           \
  } while (0)

// ---------------------------------------------------------------------------
__global__ __launch_bounds__(256) void convert1_kernel(
    const float* __restrict__ xv, const float* __restrict__ xi,
    const float* __restrict__ w, bf16* __restrict__ dst)
{
  const size_t NV = 9437184;     // 12288*768
  const size_t NX = 18874368;    // 2*NV
  const size_t NT = 20643840;    // NX + 1769472 (qkv_w)
  for (size_t i = (size_t)blockIdx.x * 256 + threadIdx.x; i * 8 < NT;
       i += (size_t)gridDim.x * 256) {
    size_t e = i * 8;
    const float* src;
    if (e < NV)      src = xv + e;
    else if (e < NX) src = xi + (e - NV);
    else             src = w + (e - NX);
    f32x4 a = *(const f32x4*)src;
    f32x4 b = *(const f32x4*)(src + 4);
    bf16x8 r;
    r[0] = (bf16)a[0]; r[1] = (bf16)a[1]; r[2] = (bf16)a[2]; r[3] = (bf16)a[3];
    r[4] = (bf16)b[0]; r[5] = (bf16)b[1]; r[6] = (bf16)b[2]; r[7] = (bf16)b[3];
    *(bf16x8*)(dst + e) = r;
  }
}

__global__ __launch_bounds__(256) void convert2_kernel(
    const float* __restrict__ w, bf16* __restrict__ dst)
{
  size_t i = (size_t)blockIdx.x * 256 + threadIdx.x;
  size_t e = i * 8;
  if (e >= 589824) return;
  f32x4 a = *(const f32x4*)(w + e);
  f32x4 b = *(const f32x4*)(w + e + 4);
  bf16x8 r;
  r[0] = (bf16)a[0]; r[1] = (bf16)a[1]; r[2] = (bf16)a[2]; r[3] = (bf16)a[3];
  r[4] = (bf16)b[0]; r[5] = (bf16)b[1]; r[6] = (bf16)b[2]; r[7] = (bf16)b[3];
  *(bf16x8*)(dst + e) = r;
}

// ---------------------------------------------------------------------------
// Kernel 1: QKV projection. 128x128 tile, BK=64. Scatter epilogue: Q scaled
// by 0.125*log2(e) (softmax uses exp2), K row-major, V transposed.
// ---------------------------------------------------------------------------
__global__ __launch_bounds__(256, 2) void qkv_kernel(
    const bf16* __restrict__ X, const bf16* __restrict__ W,
    bf16* __restrict__ Qo, bf16* __restrict__ Ko, bf16* __restrict__ VTo)
{
  __shared__ bf16 As[2][128][64];
  __shared__ bf16 Bs[2][128][64];
  int bid = blockIdx.x;                    // 3456 blocks
  int swz = (bid & 7) * 432 + (bid >> 3);  // XCD-contiguous, bijective
  const int nt = swz % 18, mt = swz / 18;
  const int m0 = mt * 128, n0 = nt * 128;
  const int tid = threadIdx.x;
  const int lane = tid & 63;
  const int wv = tid >> 6;                 // 0..3
  const int wr = (wv >> 1) * 64, wc = (wv & 1) * 64;
  const int lr = lane & 15, lg = lane >> 4;

  const bf16* Xp = X + (size_t)m0 * 768;
  const bf16* Wp = W + (size_t)n0 * 768;

  f32x4 acc[4][4] = {};

  GEMM128_LOOP(Xp, Wp, 12);

#pragma unroll
  for (int mf = 0; mf < 4; ++mf)
#pragma unroll
    for (int nf = 0; nf < 4; ++nf) {
      int m = m0 + wr + mf * 16 + lg * 4;       // 4-aligned token base
      int n = n0 + wc + nf * 16 + lr;
      int bp = m / 384, tok = m - bp * 384;
      int comp = (n >= 1536) ? 2 : (n >= 768) ? 1 : 0;
      int rem = n - comp * 768;
      int hh = rem >> 6, d = rem & 63;
      if (comp == 2) {
        bf16x4 pk;
        pk[0] = (bf16)acc[mf][nf][0]; pk[1] = (bf16)acc[mf][nf][1];
        pk[2] = (bf16)acc[mf][nf][2]; pk[3] = (bf16)acc[mf][nf][3];
        *(bf16x4*)(VTo + (((size_t)bp * 12 + hh) * 64 + d) * 384 + tok) = pk;
      } else {
#pragma unroll
        for (int r = 0; r < 4; ++r) {
          size_t addr = (((size_t)bp * 12 + hh) * 384 + tok + r) * 64 + d;
          float val = acc[mf][nf][r];
          if (comp == 0)
            Qo[addr] = (bf16)(val * 0.18033688f);  // 0.125 * log2(e)
          else
            Ko[addr] = (bf16)val;
        }
      }
    }
}

// ---------------------------------------------------------------------------
// Kernel 2: attention, swapped-QK^T lane-local softmax (exp2, tree-reduce)
// + T14 reg-prefetch. grid = 64*12*3.
// ---------------------------------------------------------------------------
__global__ __launch_bounds__(256) void attn_kernel(
    const bf16* __restrict__ Q, const bf16* __restrict__ K, const bf16* __restrict__ VT,
    bf16* __restrict__ ATT)
{
  __shared__ union {
    bf16 Qs[128][72];
    bf16 Ps[4][32][136];     // per-wave P tile [q_local][key] (Qs dead after qf cache)
  } u;
  __shared__ bf16 Ks[128][72];
  __shared__ bf16 VTs[64][136];     // transposed V: [d][token]

  const int bid = blockIdx.x;
  const int qb = bid % 3;
  const int h  = (bid / 3) % 12;
  const int bp = bid / 36;           // b' in [0,64)
  const int tid = threadIdx.x;
  const int lane = tid & 63;
  const int wv = tid >> 6;
  const int lr = lane & 15, lg = lane >> 4;

  const size_t bh384 = ((size_t)bp * 12 + h) * 384;
  const int q0 = qb * 128;
  const int nchunks = (qb == 0) ? 1 : 4;

  // chunk -> (src_b, t0)
  auto chunk_base = [&](int c, size_t& kb, size_t& vtb) {
    int src_b, t0;
    if (qb == 0)      { src_b = bp;             t0 = 0; }
    else if (c == 0)  { src_b = bp & 31;        t0 = 0; }
    else if (c == 1)  { src_b = (bp & 31) + 32; t0 = 0; }
    else              { src_b = bp;             t0 = (c - 1) * 128; }
    kb  = (((size_t)src_b * 12 + h) * 384 + t0) * 64;
    vtb = ((size_t)src_b * 12 + h) * 64 * 384 + t0;
  };

  for (int v = tid; v < 1024; v += 256) {
    int row = v >> 3, cg = (v & 7) * 8;
    *(bf16x8*)(&u.Qs[row][cg]) = *(const bf16x8*)(Q + (bh384 + q0 + row) * 64 + cg);
  }
  __syncthreads();

  bf16x8 qf[2][2];
#pragma unroll
  for (int mf = 0; mf < 2; ++mf)
#pragma unroll
    for (int ks = 0; ks < 2; ++ks)
      qf[mf][ks] = *(const bf16x8*)(&u.Qs[wv * 32 + mf * 16 + lr][ks * 32 + lg * 8]);

  // --- T14: registers holding the NEXT chunk's K and VT tiles ------------
  const int krow = tid >> 3,  kcg = (tid & 7) * 8;    // K: rows 0..31 (+32i)
  const int vd   = tid >> 4,  vp  = (tid & 15) * 8;   // VT: d 0..15 (+16i)
  bf16x8 kreg[4], vreg[4];
  {
    size_t kb, vtb; chunk_base(0, kb, vtb);
#pragma unroll
    for (int i = 0; i < 4; ++i) {
      kreg[i] = *(const bf16x8*)(K + kb + (size_t)(krow + i * 32) * 64 + kcg);
      vreg[i] = *(const bf16x8*)(VT + vtb + (size_t)(vd + i * 16) * 384 + vp);
    }
  }

  f32x4 O[2][4] = {};
  float runmax[2] = {-1e30f, -1e30f}, runsum[2] = {0.f, 0.f};

  for (int c = 0; c < nchunks; ++c) {
    __syncthreads();   // previous chunk fully consumed before restaging
#pragma unroll
    for (int i = 0; i < 4; ++i) {
      *(bf16x8*)(&Ks[krow + i * 32][kcg]) = kreg[i];
      *(bf16x8*)(&VTs[vd + i * 16][vp])   = vreg[i];
    }
    __syncthreads();

    if (c + 1 < nchunks) {     // prefetch next chunk into regs (no wait here)
      size_t kb, vtb; chunk_base(c + 1, kb, vtb);
#pragma unroll
      for (int i = 0; i < 4; ++i) {
        kreg[i] = *(const bf16x8*)(K + kb + (size_t)(krow + i * 32) * 64 + kcg);
        vreg[i] = *(const bf16x8*)(VT + vtb + (size_t)(vd + i * 16) * 384 + vp);
      }
    }

    // St = K * Q^T (swapped): lane holds St[key = nf*16+lg*4+r][q = mf*16+lr]
    // (already in log2 domain: Q pre-scaled by 0.125*log2e)
    f32x4 St[2][8] = {};
#pragma unroll
    for (int nf = 0; nf < 8; ++nf) {
#pragma unroll
      for (int ks = 0; ks < 2; ++ks) {
        bf16x8 kf = *(const bf16x8*)(&Ks[nf * 16 + lr][ks * 32 + lg * 8]);
        St[0][nf] = MFMA16(kf, qf[0][ks], St[0][nf]);
        St[1][nf] = MFMA16(kf, qf[1][ks], St[1][nf]);
      }
    }

    // online softmax (exp2 domain); tree reductions (depth 5, not 31-serial)
    float rfq[2];
#pragma unroll
    for (int mf = 0; mf < 2; ++mf) {
      float v[32];
#pragma unroll
      for (int nf = 0; nf < 8; ++nf)
#pragma unroll
        for (int r = 0; r < 4; ++r) v[nf * 4 + r] = St[mf][nf][r];
      float tm[16];
#pragma unroll
      for (int i = 0; i < 16; ++i) tm[i] = fmaxf(v[i], v[i + 16]);
#pragma unroll
      for (int i = 0; i < 8; ++i) tm[i] = fmaxf(tm[i], tm[i + 8]);
#pragma unroll
      for (int i = 0; i < 4; ++i) tm[i] = fmaxf(tm[i], tm[i + 4]);
      float mx = fmaxf(fmaxf(tm[0], tm[1]), fmaxf(tm[2], tm[3]));
      mx = fmaxf(mx, __shfl_xor(mx, 16));
      mx = fmaxf(mx, __shfl_xor(mx, 32));
      float nm = fmaxf(runmax[mf], mx);
      rfq[mf] = exp2f(runmax[mf] - nm);
      runmax[mf] = nm;
      float p[32];
#pragma unroll
      for (int i = 0; i < 32; ++i) p[i] = exp2f(v[i] - nm);
#pragma unroll
      for (int nf = 0; nf < 8; ++nf)
#pragma unroll
        for (int r = 0; r < 4; ++r) St[mf][nf][r] = p[nf * 4 + r];
#pragma unroll
      for (int i = 0; i < 16; ++i) p[i] += p[i + 16];
#pragma unroll
      for (int i = 0; i < 8; ++i) p[i] += p[i + 8];
#pragma unroll
      for (int i = 0; i < 4; ++i) p[i] += p[i + 4];
      float rs = (p[0] + p[1]) + (p[2] + p[3]);
      rs += __shfl_xor(rs, 16);
      rs += __shfl_xor(rs, 32);
      runsum[mf] = runsum[mf] * rfq[mf] + rs;
    }

    // P write: lane holds 4 consecutive keys per (mf,nf) -> packed b64 store
#pragma unroll
    for (int mf = 0; mf < 2; ++mf)
#pragma unroll
      for (int nf = 0; nf < 8; ++nf) {
        bf16x4 pk;
        pk[0] = (bf16)St[mf][nf][0]; pk[1] = (bf16)St[mf][nf][1];
        pk[2] = (bf16)St[mf][nf][2]; pk[3] = (bf16)St[mf][nf][3];
        *(bf16x4*)(&u.Ps[wv][mf * 16 + lr][nf * 16 + lg * 4]) = pk;
      }

    // O rescale: O-row q' = mf*16 + lg*4 + r -> pull rf from lane lr'=lg*4+r
#pragma unroll
    for (int mf = 0; mf < 2; ++mf)
#pragma unroll
      for (int r = 0; r < 4; ++r) {
        float rr = __shfl(rfq[mf], (lg * 4 + r) + (lg << 4));
#pragma unroll
        for (int vn = 0; vn < 4; ++vn) O[mf][vn][r] *= rr;
      }

#pragma unroll
    for (int ks = 0; ks < 4; ++ks) {
      bf16x8 pf0 = *(const bf16x8*)(&u.Ps[wv][lr][ks * 32 + lg * 8]);
      bf16x8 pf1 = *(const bf16x8*)(&u.Ps[wv][16 + lr][ks * 32 + lg * 8]);
#pragma unroll
      for (int vn = 0; vn < 4; ++vn) {
        bf16x8 vf = *(const bf16x8*)(&VTs[vn * 16 + lr][ks * 32 + lg * 8]);
        O[0][vn] = MFMA16(pf0, vf, O[0][vn]);
        O[1][vn] = MFMA16(pf1, vf, O[1][vn]);
      }
    }
  }

  // epilogue: divide by runsum of O-row q' (pull from lane lr' = lg*4+r)
#pragma unroll
  for (int mf = 0; mf < 2; ++mf) {
#pragma unroll
    for (int r = 0; r < 4; ++r) {
      float rs = __shfl(runsum[mf], (lg * 4 + r) + (lg << 4));
      float inv = 1.0f / rs;
#pragma unroll
      for (int vn = 0; vn < 4; ++vn) {
        int tok = q0 + wv * 32 + mf * 16 + lg * 4 + r;
        int d = vn * 16 + lr;
        ATT[((size_t)bp * 384 + tok) * 768 + h * 64 + d] = (bf16)(O[mf][vn][r] * inv);
      }
    }
  }
}

// ---------------------------------------------------------------------------
// Kernel 3: output projection. 128x128 tile, BK=64, f32 out + bias.
// ---------------------------------------------------------------------------
__global__ __launch_bounds__(256, 2) void proj_kernel(
    const bf16* __restrict__ A, const bf16* __restrict__ W,
    const float* __restrict__ bias, float* __restrict__ out)
{
  __shared__ bf16 As[2][128][64];
  __shared__ bf16 Bs[2][128][64];
  int bid = blockIdx.x;                    // 1152 blocks
  int swz = (bid & 7) * 144 + (bid >> 3);  // 1152 = 8*144
  const int nt = swz % 6, mt = swz / 6;
  const int m0 = mt * 128, n0 = nt * 128;
  const int tid = threadIdx.x;
  const int lane = tid & 63;
  const int wv = tid >> 6;
  const int wr = (wv >> 1) * 64, wc = (wv & 1) * 64;
  const int lr = lane & 15, lg = lane >> 4;

  const bf16* Ap = A + (size_t)m0 * 768;
  const bf16* Wpp = W + (size_t)n0 * 768;

  f32x4 acc[4][4] = {};

  GEMM128_LOOP(Ap, Wpp, 12);

#pragma unroll
  for (int mf = 0; mf < 4; ++mf)
#pragma unroll
    for (int nf = 0; nf < 4; ++nf)
#pragma unroll
      for (int r = 0; r < 4; ++r) {
        int m = m0 + wr + mf * 16 + lg * 4 + r;
        int n = n0 + wc + nf * 16 + lr;
        out[(size_t)m * 768 + n] = acc[mf][nf][r] + bias[n];
      }
}

// ---------------------------------------------------------------------------
extern "C" void kernel_launch(void* const* d_in, const int* in_sizes, int n_in,
                              void* d_out, int out_size, void* d_ws, size_t ws_size,
                              hipStream_t stream) {
  (void)in_sizes; (void)n_in; (void)out_size; (void)ws_size;
  const float* xv     = (const float*)d_in[0];
  const float* xi     = (const float*)d_in[1];
  const float* qkv_w  = (const float*)d_in[2];
  const float* proj_w = (const float*)d_in[3];
  const float* proj_b = (const float*)d_in[4];
  float* out = (float*)d_out;

  // bf16 scratch inside d_out (75.5 MB): Xb [24576][768] then Wq [2304][768].
  bf16* Xb = (bf16*)d_out;
  bf16* Wq = Xb + (size_t)18874368;

  // ws: Q | K | VT | ATT, each 18874368 bf16 (~36 MB) = 151 MB total.
  const size_t SZ = (size_t)64 * 12 * 384 * 64;
  bf16* Q   = (bf16*)d_ws;
  bf16* K   = Q + SZ;
  bf16* VT  = K + SZ;
  bf16* ATT = VT + SZ;
  bf16* Wp  = Q;                 // proj_w bf16, reuses Q region after attn

  convert1_kernel<<<2048, 256, 0, stream>>>(xv, xi, qkv_w, Xb);
  qkv_kernel<<<3456, 256, 0, stream>>>(Xb, Wq, Q, K, VT);
  attn_kernel<<<64 * 12 * 3, 256, 0, stream>>>(Q, K, VT, ATT);
  convert2_kernel<<<288, 256, 0, stream>>>(proj_w, Wp);
  proj_kernel<<<1152, 256, 0, stream>>>(ATT, Wp, proj_b, out);
}

// Round 14
// 263.936 us; speedup vs baseline: 1.0012x; 1.0012x over previous
//
#include <hip/hip_runtime.h>

typedef __bf16 bf16;
typedef __bf16 bf16x4 __attribute__((ext_vector_type(4)));
typedef __bf16 bf16x8 __attribute__((ext_vector_type(8)));
typedef float f32x4 __attribute__((ext_vector_type(4)));

#define MFMA16(a,b,c) __builtin_amdgcn_mfma_f32_16x16x32_bf16((a),(b),(c),0,0,0)
#define SBAR() __builtin_amdgcn_s_barrier()
#define SCHED0() __builtin_amdgcn_sched_barrier(0)

// Shapes (fixed): B=32, N=384, C=768, H=12, Dh=64, mt=128, 2B=64 batches.
// Global inputs/outputs FLOAT32; intermediates bf16.
// Xb (x bf16 [24576][768]) + Wq (qkv_w bf16 [2304][768]) live in d_out scratch.
// ws: Q | K | VT | ATT (each 36 MB bf16) = 151 MB; Wp reuses Q after attn.
// V stored TRANSPOSED (VT[b'][h][d][tok]) by the qkv epilogue.
//
// r14 (r12 base = 249us best): softmax = r12 structure, but
//  (a) exp2 domain (Q pre-scaled by 0.125*log2e; v_exp_f32 IS 2^x -> saves
//      64 v_mul/chunk/lane vs __expf),
//  (b) in-place depth-5 reductions with only 8 temps (r13's v[32]/p[32]
//      copies added ~96 v_mov/chunk/lane -> regressed; this keeps r12's
//      register profile).

__device__ inline void gload16(const bf16* g, bf16* l) {
  __builtin_amdgcn_global_load_lds(
      (const __attribute__((address_space(1))) void*)g,
      (__attribute__((address_space(3))) void*)l, 16, 0, 0);
}

__device__ inline void stage128(const bf16* __restrict__ gsrc,
                                bf16* lds_base, int tid, int wv) {
#pragma unroll
  for (int r = 0; r < 4; ++r) {
    int s = r * 256 + tid;                        // 0..1023
    int row = s >> 3;
    int chunk = (s & 7) ^ (row & 7);
    gload16(gsrc + (size_t)row * 768 + chunk * 8,
            lds_base + (size_t)(r * 256 + wv * 64) * 8);
  }
}

__device__ inline bf16x8 frag64(const bf16* buf, int row, int ks, int lg) {
  int slot = ((ks << 2) | lg) ^ (row & 7);
  return *(const bf16x8*)(buf + (size_t)row * 64 + slot * 8);
}

// Counted-vmcnt K-loop over NTILES tiles of BK=64 (r8/r9, verified).
#define GEMM128_LOOP(APANEL, BPANEL, NTILES)                                    \
  do {                                                                          \
    stage128((APANEL), &As[0][0][0], tid, wv);                                  \
    stage128((BPANEL), &Bs[0][0][0], tid, wv);                                  \
    stage128((APANEL) + 64, &As[1][0][0], tid, wv);                             \
    stage128((BPANEL) + 64, &Bs[1][0][0], tid, wv);                             \
    asm volatile("s_waitcnt vmcnt(8)" ::: "memory"); SCHED0();                  \
    SBAR();                                                                     \
    int c = 0;                                                                  \
    for (int t = 0; t < (NTILES); ++t) {                                        \
      const bf16* Ab = &As[c][0][0];                                            \
      const bf16* Bb = &Bs[c][0][0];                                            \
      bf16x8 af[4][2], bfr[4][2];                                               \
      _Pragma("unroll")                                                         \
      for (int nf = 0; nf < 4; ++nf)                                            \
        _Pragma("unroll")                                                       \
        for (int ks = 0; ks < 2; ++ks)                                          \
          bfr[nf][ks] = frag64(Bb, wc + nf * 16 + lr, ks, lg);                  \
      _Pragma("unroll")                                                         \
      for (int mf = 0; mf < 4; ++mf)                                            \
        _Pragma("unroll")                                                       \
        for (int ks = 0; ks < 2; ++ks)                                          \
          af[mf][ks] = frag64(Ab, wr + mf * 16 + lr, ks, lg);                   \
      asm volatile("s_waitcnt lgkmcnt(0)" ::: "memory"); SCHED0();              \
      SBAR();   /* all waves done reading buf[c] -> safe to refill */           \
      if (t + 2 < (NTILES)) {                                                   \
        stage128((APANEL) + (t + 2) * 64, &As[c][0][0], tid, wv);               \
        stage128((BPANEL) + (t + 2) * 64, &Bs[c][0][0], tid, wv);               \
      }                                                                         \
      __builtin_amdgcn_s_setprio(1);                                            \
      _Pragma("unroll")                                                         \
      for (int mf = 0; mf < 4; ++mf)                                            \
        _Pragma("unroll")                                                       \
        for (int nf = 0; nf < 4; ++nf)                                          \
          _Pragma("unroll")                                                     \
          for (int ks = 0; ks < 2; ++ks)                                        \
            acc[mf][nf] = MFMA16(af[mf][ks], bfr[nf][ks], acc[mf][nf]);         \
      __builtin_amdgcn_s_setprio(0);                                            \
      if (t + 2 < (NTILES)) { asm volatile("s_waitcnt vmcnt(8)" ::: "memory"); }\
      else                  { asm volatile("s_waitcnt vmcnt(0)" ::: "memory"); }\
      SCHED0();                                                                 \
      SBAR();   /* buf[c^1] (tile t+1) now globally ready */                    \
      c ^= 1;                                                                   \
    }                                                                           \
  } while (0)

// ---------------------------------------------------------------------------
__global__ __launch_bounds__(256) void convert1_kernel(
    const float* __restrict__ xv, const float* __restrict__ xi,
    const float* __restrict__ w, bf16* __restrict__ dst)
{
  const size_t NV = 9437184;     // 12288*768
  const size_t NX = 18874368;    // 2*NV
  const size_t NT = 20643840;    // NX + 1769472 (qkv_w)
  for (size_t i = (size_t)blockIdx.x * 256 + threadIdx.x; i * 8 < NT;
       i += (size_t)gridDim.x * 256) {
    size_t e = i * 8;
    const float* src;
    if (e < NV)      src = xv + e;
    else if (e < NX) src = xi + (e - NV);
    else             src = w + (e - NX);
    f32x4 a = *(const f32x4*)src;
    f32x4 b = *(const f32x4*)(src + 4);
    bf16x8 r;
    r[0] = (bf16)a[0]; r[1] = (bf16)a[1]; r[2] = (bf16)a[2]; r[3] = (bf16)a[3];
    r[4] = (bf16)b[0]; r[5] = (bf16)b[1]; r[6] = (bf16)b[2]; r[7] = (bf16)b[3];
    *(bf16x8*)(dst + e) = r;
  }
}

__global__ __launch_bounds__(256) void convert2_kernel(
    const float* __restrict__ w, bf16* __restrict__ dst)
{
  size_t i = (size_t)blockIdx.x * 256 + threadIdx.x;
  size_t e = i * 8;
  if (e >= 589824) return;
  f32x4 a = *(const f32x4*)(w + e);
  f32x4 b = *(const f32x4*)(w + e + 4);
  bf16x8 r;
  r[0] = (bf16)a[0]; r[1] = (bf16)a[1]; r[2] = (bf16)a[2]; r[3] = (bf16)a[3];
  r[4] = (bf16)b[0]; r[5] = (bf16)b[1]; r[6] = (bf16)b[2]; r[7] = (bf16)b[3];
  *(bf16x8*)(dst + e) = r;
}

// ---------------------------------------------------------------------------
// Kernel 1: QKV projection. 128x128 tile, BK=64. Scatter epilogue: Q scaled
// by 0.125*log2(e) (softmax uses exp2), K row-major, V transposed.
// ---------------------------------------------------------------------------
__global__ __launch_bounds__(256, 2) void qkv_kernel(
    const bf16* __restrict__ X, const bf16* __restrict__ W,
    bf16* __restrict__ Qo, bf16* __restrict__ Ko, bf16* __restrict__ VTo)
{
  __shared__ bf16 As[2][128][64];
  __shared__ bf16 Bs[2][128][64];
  int bid = blockIdx.x;                    // 3456 blocks
  int swz = (bid & 7) * 432 + (bid >> 3);  // XCD-contiguous, bijective
  const int nt = swz % 18, mt = swz / 18;
  const int m0 = mt * 128, n0 = nt * 128;
  const int tid = threadIdx.x;
  const int lane = tid & 63;
  const int wv = tid >> 6;                 // 0..3
  const int wr = (wv >> 1) * 64, wc = (wv & 1) * 64;
  const int lr = lane & 15, lg = lane >> 4;

  const bf16* Xp = X + (size_t)m0 * 768;
  const bf16* Wp = W + (size_t)n0 * 768;

  f32x4 acc[4][4] = {};

  GEMM128_LOOP(Xp, Wp, 12);

#pragma unroll
  for (int mf = 0; mf < 4; ++mf)
#pragma unroll
    for (int nf = 0; nf < 4; ++nf) {
      int m = m0 + wr + mf * 16 + lg * 4;       // 4-aligned token base
      int n = n0 + wc + nf * 16 + lr;
      int bp = m / 384, tok = m - bp * 384;
      int comp = (n >= 1536) ? 2 : (n >= 768) ? 1 : 0;
      int rem = n - comp * 768;
      int hh = rem >> 6, d = rem & 63;
      if (comp == 2) {
        bf16x4 pk;
        pk[0] = (bf16)acc[mf][nf][0]; pk[1] = (bf16)acc[mf][nf][1];
        pk[2] = (bf16)acc[mf][nf][2]; pk[3] = (bf16)acc[mf][nf][3];
        *(bf16x4*)(VTo + (((size_t)bp * 12 + hh) * 64 + d) * 384 + tok) = pk;
      } else {
#pragma unroll
        for (int r = 0; r < 4; ++r) {
          size_t addr = (((size_t)bp * 12 + hh) * 384 + tok + r) * 64 + d;
          float val = acc[mf][nf][r];
          if (comp == 0)
            Qo[addr] = (bf16)(val * 0.18033688f);  // 0.125 * log2(e)
          else
            Ko[addr] = (bf16)val;
        }
      }
    }
}

// ---------------------------------------------------------------------------
// Kernel 2: attention, swapped-QK^T lane-local softmax (exp2, in-place
// depth-5 reduce, 8 temps) + T14 reg-prefetch. grid = 64*12*3.
// ---------------------------------------------------------------------------
__global__ __launch_bounds__(256) void attn_kernel(
    const bf16* __restrict__ Q, const bf16* __restrict__ K, const bf16* __restrict__ VT,
    bf16* __restrict__ ATT)
{
  __shared__ union {
    bf16 Qs[128][72];
    bf16 Ps[4][32][136];     // per-wave P tile [q_local][key] (Qs dead after qf cache)
  } u;
  __shared__ bf16 Ks[128][72];
  __shared__ bf16 VTs[64][136];     // transposed V: [d][token]

  const int bid = blockIdx.x;
  const int qb = bid % 3;
  const int h  = (bid / 3) % 12;
  const int bp = bid / 36;           // b' in [0,64)
  const int tid = threadIdx.x;
  const int lane = tid & 63;
  const int wv = tid >> 6;
  const int lr = lane & 15, lg = lane >> 4;

  const size_t bh384 = ((size_t)bp * 12 + h) * 384;
  const int q0 = qb * 128;
  const int nchunks = (qb == 0) ? 1 : 4;

  // chunk -> (src_b, t0)
  auto chunk_base = [&](int c, size_t& kb, size_t& vtb) {
    int src_b, t0;
    if (qb == 0)      { src_b = bp;             t0 = 0; }
    else if (c == 0)  { src_b = bp & 31;        t0 = 0; }
    else if (c == 1)  { src_b = (bp & 31) + 32; t0 = 0; }
    else              { src_b = bp;             t0 = (c - 1) * 128; }
    kb  = (((size_t)src_b * 12 + h) * 384 + t0) * 64;
    vtb = ((size_t)src_b * 12 + h) * 64 * 384 + t0;
  };

  for (int v = tid; v < 1024; v += 256) {
    int row = v >> 3, cg = (v & 7) * 8;
    *(bf16x8*)(&u.Qs[row][cg]) = *(const bf16x8*)(Q + (bh384 + q0 + row) * 64 + cg);
  }
  __syncthreads();

  bf16x8 qf[2][2];
#pragma unroll
  for (int mf = 0; mf < 2; ++mf)
#pragma unroll
    for (int ks = 0; ks < 2; ++ks)
      qf[mf][ks] = *(const bf16x8*)(&u.Qs[wv * 32 + mf * 16 + lr][ks * 32 + lg * 8]);

  // --- T14: registers holding the NEXT chunk's K and VT tiles ------------
  const int krow = tid >> 3,  kcg = (tid & 7) * 8;    // K: rows 0..31 (+32i)
  const int vd   = tid >> 4,  vp  = (tid & 15) * 8;   // VT: d 0..15 (+16i)
  bf16x8 kreg[4], vreg[4];
  {
    size_t kb, vtb; chunk_base(0, kb, vtb);
#pragma unroll
    for (int i = 0; i < 4; ++i) {
      kreg[i] = *(const bf16x8*)(K + kb + (size_t)(krow + i * 32) * 64 + kcg);
      vreg[i] = *(const bf16x8*)(VT + vtb + (size_t)(vd + i * 16) * 384 + vp);
    }
  }

  f32x4 O[2][4] = {};
  float runmax[2] = {-1e30f, -1e30f}, runsum[2] = {0.f, 0.f};

  for (int c = 0; c < nchunks; ++c) {
    __syncthreads();   // previous chunk fully consumed before restaging
#pragma unroll
    for (int i = 0; i < 4; ++i) {
      *(bf16x8*)(&Ks[krow + i * 32][kcg]) = kreg[i];
      *(bf16x8*)(&VTs[vd + i * 16][vp])   = vreg[i];
    }
    __syncthreads();

    if (c + 1 < nchunks) {     // prefetch next chunk into regs (no wait here)
      size_t kb, vtb; chunk_base(c + 1, kb, vtb);
#pragma unroll
      for (int i = 0; i < 4; ++i) {
        kreg[i] = *(const bf16x8*)(K + kb + (size_t)(krow + i * 32) * 64 + kcg);
        vreg[i] = *(const bf16x8*)(VT + vtb + (size_t)(vd + i * 16) * 384 + vp);
      }
    }

    // St = K * Q^T (swapped): lane holds St[key = nf*16+lg*4+r][q = mf*16+lr]
    // (already in log2 domain: Q pre-scaled by 0.125*log2e)
    f32x4 St[2][8] = {};
#pragma unroll
    for (int nf = 0; nf < 8; ++nf) {
#pragma unroll
      for (int ks = 0; ks < 2; ++ks) {
        bf16x8 kf = *(const bf16x8*)(&Ks[nf * 16 + lr][ks * 32 + lg * 8]);
        St[0][nf] = MFMA16(kf, qf[0][ks], St[0][nf]);
        St[1][nf] = MFMA16(kf, qf[1][ks], St[1][nf]);
      }
    }

    // online softmax (exp2 domain), in-place, depth-5 trees w/ 8 temps
    float rfq[2];
#pragma unroll
    for (int mf = 0; mf < 2; ++mf) {
      float m4[8];
#pragma unroll
      for (int nf = 0; nf < 8; ++nf)
        m4[nf] = fmaxf(fmaxf(St[mf][nf][0], St[mf][nf][1]),
                       fmaxf(St[mf][nf][2], St[mf][nf][3]));
      float mx = fmaxf(fmaxf(fmaxf(m4[0], m4[1]), fmaxf(m4[2], m4[3])),
                       fmaxf(fmaxf(m4[4], m4[5]), fmaxf(m4[6], m4[7])));
      mx = fmaxf(mx, __shfl_xor(mx, 16));
      mx = fmaxf(mx, __shfl_xor(mx, 32));
      float nm = fmaxf(runmax[mf], mx);
      rfq[mf] = exp2f(runmax[mf] - nm);
      runmax[mf] = nm;
      float s4[8];
#pragma unroll
      for (int nf = 0; nf < 8; ++nf) {
        St[mf][nf][0] = exp2f(St[mf][nf][0] - nm);
        St[mf][nf][1] = exp2f(St[mf][nf][1] - nm);
        St[mf][nf][2] = exp2f(St[mf][nf][2] - nm);
        St[mf][nf][3] = exp2f(St[mf][nf][3] - nm);
        s4[nf] = (St[mf][nf][0] + St[mf][nf][1]) + (St[mf][nf][2] + St[mf][nf][3]);
      }
      float rs = ((s4[0] + s4[1]) + (s4[2] + s4[3])) +
                 ((s4[4] + s4[5]) + (s4[6] + s4[7]));
      rs += __shfl_xor(rs, 16);
      rs += __shfl_xor(rs, 32);
      runsum[mf] = runsum[mf] * rfq[mf] + rs;
    }

    // P write: lane holds 4 consecutive keys per (mf,nf) -> packed b64 store
#pragma unroll
    for (int mf = 0; mf < 2; ++mf)
#pragma unroll
      for (int nf = 0; nf < 8; ++nf) {
        bf16x4 pk;
        pk[0] = (bf16)St[mf][nf][0]; pk[1] = (bf16)St[mf][nf][1];
        pk[2] = (bf16)St[mf][nf][2]; pk[3] = (bf16)St[mf][nf][3];
        *(bf16x4*)(&u.Ps[wv][mf * 16 + lr][nf * 16 + lg * 4]) = pk;
      }

    // O rescale: O-row q' = mf*16 + lg*4 + r -> pull rf from lane lr'=lg*4+r
#pragma unroll
    for (int mf = 0; mf < 2; ++mf)
#pragma unroll
      for (int r = 0; r < 4; ++r) {
        float rr = __shfl(rfq[mf], (lg * 4 + r) + (lg << 4));
#pragma unroll
        for (int vn = 0; vn < 4; ++vn) O[mf][vn][r] *= rr;
      }

#pragma unroll
    for (int ks = 0; ks < 4; ++ks) {
      bf16x8 pf0 = *(const bf16x8*)(&u.Ps[wv][lr][ks * 32 + lg * 8]);
      bf16x8 pf1 = *(const bf16x8*)(&u.Ps[wv][16 + lr][ks * 32 + lg * 8]);
#pragma unroll
      for (int vn = 0; vn < 4; ++vn) {
        bf16x8 vf = *(const bf16x8*)(&VTs[vn * 16 + lr][ks * 32 + lg * 8]);
        O[0][vn] = MFMA16(pf0, vf, O[0][vn]);
        O[1][vn] = MFMA16(pf1, vf, O[1][vn]);
      }
    }
  }

  // epilogue: divide by runsum of O-row q' (pull from lane lr' = lg*4+r)
#pragma unroll
  for (int mf = 0; mf < 2; ++mf) {
#pragma unroll
    for (int r = 0; r < 4; ++r) {
      float rs = __shfl(runsum[mf], (lg * 4 + r) + (lg << 4));
      float inv = 1.0f / rs;
#pragma unroll
      for (int vn = 0; vn < 4; ++vn) {
        int tok = q0 + wv * 32 + mf * 16 + lg * 4 + r;
        int d = vn * 16 + lr;
        ATT[((size_t)bp * 384 + tok) * 768 + h * 64 + d] = (bf16)(O[mf][vn][r] * inv);
      }
    }
  }
}

// ---------------------------------------------------------------------------
// Kernel 3: output projection. 128x128 tile, BK=64, f32 out + bias.
// ---------------------------------------------------------------------------
__global__ __launch_bounds__(256, 2) void proj_kernel(
    const bf16* __restrict__ A, const bf16* __restrict__ W,
    const float* __restrict__ bias, float* __restrict__ out)
{
  __shared__ bf16 As[2][128][64];
  __shared__ bf16 Bs[2][128][64];
  int bid = blockIdx.x;                    // 1152 blocks
  int swz = (bid & 7) * 144 + (bid >> 3);  // 1152 = 8*144
  const int nt = swz % 6, mt = swz / 6;
  const int m0 = mt * 128, n0 = nt * 128;
  const int tid = threadIdx.x;
  const int lane = tid & 63;
  const int wv = tid >> 6;
  const int wr = (wv >> 1) * 64, wc = (wv & 1) * 64;
  const int lr = lane & 15, lg = lane >> 4;

  const bf16* Ap = A + (size_t)m0 * 768;
  const bf16* Wpp = W + (size_t)n0 * 768;

  f32x4 acc[4][4] = {};

  GEMM128_LOOP(Ap, Wpp, 12);

#pragma unroll
  for (int mf = 0; mf < 4; ++mf)
#pragma unroll
    for (int nf = 0; nf < 4; ++nf)
#pragma unroll
      for (int r = 0; r < 4; ++r) {
        int m = m0 + wr + mf * 16 + lg * 4 + r;
        int n = n0 + wc + nf * 16 + lr;
        out[(size_t)m * 768 + n] = acc[mf][nf][r] + bias[n];
      }
}

// ---------------------------------------------------------------------------
extern "C" void kernel_launch(void* const* d_in, const int* in_sizes, int n_in,
                              void* d_out, int out_size, void* d_ws, size_t ws_size,
                              hipStream_t stream) {
  (void)in_sizes; (void)n_in; (void)out_size; (void)ws_size;
  const float* xv     = (const float*)d_in[0];
  const float* xi     = (const float*)d_in[1];
  const float* qkv_w  = (const float*)d_in[2];
  const float* proj_w = (const float*)d_in[3];
  const float* proj_b = (const float*)d_in[4];
  float* out = (float*)d_out;

  // bf16 scratch inside d_out (75.5 MB): Xb [24576][768] then Wq [2304][768].
  bf16* Xb = (bf16*)d_out;
  bf16* Wq = Xb + (size_t)18874368;

  // ws: Q | K | VT | ATT, each 18874368 bf16 (~36 MB) = 151 MB total.
  const size_t SZ = (size_t)64 * 12 * 384 * 64;
  bf16* Q   = (bf16*)d_ws;
  bf16* K   = Q + SZ;
  bf16* VT  = K + SZ;
  bf16* ATT = VT + SZ;
  bf16* Wp  = Q;                 // proj_w bf16, reuses Q region after attn

  convert1_kernel<<<2048, 256, 0, stream>>>(xv, xi, qkv_w, Xb);
  qkv_kernel<<<3456, 256, 0, stream>>>(Xb, Wq, Q, K, VT);
  attn_kernel<<<64 * 12 * 3, 256, 0, stream>>>(Q, K, VT, ATT);
  convert2_kernel<<<288, 256, 0, stream>>>(proj_w, Wp);
  proj_kernel<<<1152, 256, 0, stream>>>(ATT, Wp, proj_b, out);
}

// Round 15
// 246.778 us; speedup vs baseline: 1.0709x; 1.0695x over previous
//
#include <hip/hip_runtime.h>

typedef __bf16 bf16;
typedef __bf16 bf16x4 __attribute__((ext_vector_type(4)));
typedef __bf16 bf16x8 __attribute__((ext_vector_type(8)));
typedef float f32x4 __attribute__((ext_vector_type(4)));

#define MFMA16(a,b,c) __builtin_amdgcn_mfma_f32_16x16x32_bf16((a),(b),(c),0,0,0)
#define SBAR() __builtin_amdgcn_s_barrier()
#define SCHED0() __builtin_amdgcn_sched_barrier(0)
#define EXP2(x) __builtin_amdgcn_exp2f(x)   // bare v_exp_f32 (= 2^x), no libm fixup

// Shapes (fixed): B=32, N=384, C=768, H=12, Dh=64, mt=128, 2B=64 batches.
// Global inputs/outputs FLOAT32; intermediates bf16.
// Xb (x bf16 [24576][768]) + Wq (qkv_w bf16 [2304][768]) live in d_out scratch.
// ws: Q | K | VT | ATT (each 36 MB bf16) = 151 MB; Wp reuses Q after attn.
// V stored TRANSPOSED (VT[b'][h][d][tok]) by the qkv epilogue.
//
// r15: r13/r14's regression was libm exp2f (carries denorm/range fixup,
// ~8 extra VALU/call vs __expf's 2). Fix: __builtin_amdgcn_exp2f = bare
// v_exp_f32. With Q pre-scaled by 0.125*log2e this is 1 op per exp —
// cheaper than r12's __expf (v_mul+v_exp). Tree reduce + in-place kept.

__device__ inline void gload16(const bf16* g, bf16* l) {
  __builtin_amdgcn_global_load_lds(
      (const __attribute__((address_space(1))) void*)g,
      (__attribute__((address_space(3))) void*)l, 16, 0, 0);
}

__device__ inline void stage128(const bf16* __restrict__ gsrc,
                                bf16* lds_base, int tid, int wv) {
#pragma unroll
  for (int r = 0; r < 4; ++r) {
    int s = r * 256 + tid;                        // 0..1023
    int row = s >> 3;
    int chunk = (s & 7) ^ (row & 7);
    gload16(gsrc + (size_t)row * 768 + chunk * 8,
            lds_base + (size_t)(r * 256 + wv * 64) * 8);
  }
}

__device__ inline bf16x8 frag64(const bf16* buf, int row, int ks, int lg) {
  int slot = ((ks << 2) | lg) ^ (row & 7);
  return *(const bf16x8*)(buf + (size_t)row * 64 + slot * 8);
}

// Counted-vmcnt K-loop over NTILES tiles of BK=64 (r8/r9, verified).
#define GEMM128_LOOP(APANEL, BPANEL, NTILES)                                    \
  do {                                                                          \
    stage128((APANEL), &As[0][0][0], tid, wv);                                  \
    stage128((BPANEL), &Bs[0][0][0], tid, wv);                                  \
    stage128((APANEL) + 64, &As[1][0][0], tid, wv);                             \
    stage128((BPANEL) + 64, &Bs[1][0][0], tid, wv);                             \
    asm volatile("s_waitcnt vmcnt(8)" ::: "memory"); SCHED0();                  \
    SBAR();                                                                     \
    int c = 0;                                                                  \
    for (int t = 0; t < (NTILES); ++t) {                                        \
      const bf16* Ab = &As[c][0][0];                                            \
      const bf16* Bb = &Bs[c][0][0];                                            \
      bf16x8 af[4][2], bfr[4][2];                                               \
      _Pragma("unroll")                                                         \
      for (int nf = 0; nf < 4; ++nf)                                            \
        _Pragma("unroll")                                                       \
        for (int ks = 0; ks < 2; ++ks)                                          \
          bfr[nf][ks] = frag64(Bb, wc + nf * 16 + lr, ks, lg);                  \
      _Pragma("unroll")                                                         \
      for (int mf = 0; mf < 4; ++mf)                                            \
        _Pragma("unroll")                                                       \
        for (int ks = 0; ks < 2; ++ks)                                          \
          af[mf][ks] = frag64(Ab, wr + mf * 16 + lr, ks, lg);                   \
      asm volatile("s_waitcnt lgkmcnt(0)" ::: "memory"); SCHED0();              \
      SBAR();   /* all waves done reading buf[c] -> safe to refill */           \
      if (t + 2 < (NTILES)) {                                                   \
        stage128((APANEL) + (t + 2) * 64, &As[c][0][0], tid, wv);               \
        stage128((BPANEL) + (t + 2) * 64, &Bs[c][0][0], tid, wv);               \
      }                                                                         \
      __builtin_amdgcn_s_setprio(1);                                            \
      _Pragma("unroll")                                                         \
      for (int mf = 0; mf < 4; ++mf)                                            \
        _Pragma("unroll")                                                       \
        for (int nf = 0; nf < 4; ++nf)                                          \
          _Pragma("unroll")                                                     \
          for (int ks = 0; ks < 2; ++ks)                                        \
            acc[mf][nf] = MFMA16(af[mf][ks], bfr[nf][ks], acc[mf][nf]);         \
      __builtin_amdgcn_s_setprio(0);                                            \
      if (t + 2 < (NTILES)) { asm volatile("s_waitcnt vmcnt(8)" ::: "memory"); }\
      else                  { asm volatile("s_waitcnt vmcnt(0)" ::: "memory"); }\
      SCHED0();                                                                 \
      SBAR();   /* buf[c^1] (tile t+1) now globally ready */                    \
      c ^= 1;                                                                   \
    }                                                                           \
  } while (0)

// ---------------------------------------------------------------------------
__global__ __launch_bounds__(256) void convert1_kernel(
    const float* __restrict__ xv, const float* __restrict__ xi,
    const float* __restrict__ w, bf16* __restrict__ dst)
{
  const size_t NV = 9437184;     // 12288*768
  const size_t NX = 18874368;    // 2*NV
  const size_t NT = 20643840;    // NX + 1769472 (qkv_w)
  for (size_t i = (size_t)blockIdx.x * 256 + threadIdx.x; i * 8 < NT;
       i += (size_t)gridDim.x * 256) {
    size_t e = i * 8;
    const float* src;
    if (e < NV)      src = xv + e;
    else if (e < NX) src = xi + (e - NV);
    else             src = w + (e - NX);
    f32x4 a = *(const f32x4*)src;
    f32x4 b = *(const f32x4*)(src + 4);
    bf16x8 r;
    r[0] = (bf16)a[0]; r[1] = (bf16)a[1]; r[2] = (bf16)a[2]; r[3] = (bf16)a[3];
    r[4] = (bf16)b[0]; r[5] = (bf16)b[1]; r[6] = (bf16)b[2]; r[7] = (bf16)b[3];
    *(bf16x8*)(dst + e) = r;
  }
}

__global__ __launch_bounds__(256) void convert2_kernel(
    const float* __restrict__ w, bf16* __restrict__ dst)
{
  size_t i = (size_t)blockIdx.x * 256 + threadIdx.x;
  size_t e = i * 8;
  if (e >= 589824) return;
  f32x4 a = *(const f32x4*)(w + e);
  f32x4 b = *(const f32x4*)(w + e + 4);
  bf16x8 r;
  r[0] = (bf16)a[0]; r[1] = (bf16)a[1]; r[2] = (bf16)a[2]; r[3] = (bf16)a[3];
  r[4] = (bf16)b[0]; r[5] = (bf16)b[1]; r[6] = (bf16)b[2]; r[7] = (bf16)b[3];
  *(bf16x8*)(dst + e) = r;
}

// ---------------------------------------------------------------------------
// Kernel 1: QKV projection. 128x128 tile, BK=64. Scatter epilogue: Q scaled
// by 0.125*log2(e) (softmax uses exp2), K row-major, V transposed.
// ---------------------------------------------------------------------------
__global__ __launch_bounds__(256, 2) void qkv_kernel(
    const bf16* __restrict__ X, const bf16* __restrict__ W,
    bf16* __restrict__ Qo, bf16* __restrict__ Ko, bf16* __restrict__ VTo)
{
  __shared__ bf16 As[2][128][64];
  __shared__ bf16 Bs[2][128][64];
  int bid = blockIdx.x;                    // 3456 blocks
  int swz = (bid & 7) * 432 + (bid >> 3);  // XCD-contiguous, bijective
  const int nt = swz % 18, mt = swz / 18;
  const int m0 = mt * 128, n0 = nt * 128;
  const int tid = threadIdx.x;
  const int lane = tid & 63;
  const int wv = tid >> 6;                 // 0..3
  const int wr = (wv >> 1) * 64, wc = (wv & 1) * 64;
  const int lr = lane & 15, lg = lane >> 4;

  const bf16* Xp = X + (size_t)m0 * 768;
  const bf16* Wp = W + (size_t)n0 * 768;

  f32x4 acc[4][4] = {};

  GEMM128_LOOP(Xp, Wp, 12);

#pragma unroll
  for (int mf = 0; mf < 4; ++mf)
#pragma unroll
    for (int nf = 0; nf < 4; ++nf) {
      int m = m0 + wr + mf * 16 + lg * 4;       // 4-aligned token base
      int n = n0 + wc + nf * 16 + lr;
      int bp = m / 384, tok = m - bp * 384;
      int comp = (n >= 1536) ? 2 : (n >= 768) ? 1 : 0;
      int rem = n - comp * 768;
      int hh = rem >> 6, d = rem & 63;
      if (comp == 2) {
        bf16x4 pk;
        pk[0] = (bf16)acc[mf][nf][0]; pk[1] = (bf16)acc[mf][nf][1];
        pk[2] = (bf16)acc[mf][nf][2]; pk[3] = (bf16)acc[mf][nf][3];
        *(bf16x4*)(VTo + (((size_t)bp * 12 + hh) * 64 + d) * 384 + tok) = pk;
      } else {
#pragma unroll
        for (int r = 0; r < 4; ++r) {
          size_t addr = (((size_t)bp * 12 + hh) * 384 + tok + r) * 64 + d;
          float val = acc[mf][nf][r];
          if (comp == 0)
            Qo[addr] = (bf16)(val * 0.18033688f);  // 0.125 * log2(e)
          else
            Ko[addr] = (bf16)val;
        }
      }
    }
}

// ---------------------------------------------------------------------------
// Kernel 2: attention, swapped-QK^T lane-local softmax (v_exp_f32 direct,
// in-place depth-5 reduce) + T14 reg-prefetch. grid = 64*12*3.
// ---------------------------------------------------------------------------
__global__ __launch_bounds__(256) void attn_kernel(
    const bf16* __restrict__ Q, const bf16* __restrict__ K, const bf16* __restrict__ VT,
    bf16* __restrict__ ATT)
{
  __shared__ union {
    bf16 Qs[128][72];
    bf16 Ps[4][32][136];     // per-wave P tile [q_local][key] (Qs dead after qf cache)
  } u;
  __shared__ bf16 Ks[128][72];
  __shared__ bf16 VTs[64][136];     // transposed V: [d][token]

  const int bid = blockIdx.x;
  const int qb = bid % 3;
  const int h  = (bid / 3) % 12;
  const int bp = bid / 36;           // b' in [0,64)
  const int tid = threadIdx.x;
  const int lane = tid & 63;
  const int wv = tid >> 6;
  const int lr = lane & 15, lg = lane >> 4;

  const size_t bh384 = ((size_t)bp * 12 + h) * 384;
  const int q0 = qb * 128;
  const int nchunks = (qb == 0) ? 1 : 4;

  // chunk -> (src_b, t0)
  auto chunk_base = [&](int c, size_t& kb, size_t& vtb) {
    int src_b, t0;
    if (qb == 0)      { src_b = bp;             t0 = 0; }
    else if (c == 0)  { src_b = bp & 31;        t0 = 0; }
    else if (c == 1)  { src_b = (bp & 31) + 32; t0 = 0; }
    else              { src_b = bp;             t0 = (c - 1) * 128; }
    kb  = (((size_t)src_b * 12 + h) * 384 + t0) * 64;
    vtb = ((size_t)src_b * 12 + h) * 64 * 384 + t0;
  };

  for (int v = tid; v < 1024; v += 256) {
    int row = v >> 3, cg = (v & 7) * 8;
    *(bf16x8*)(&u.Qs[row][cg]) = *(const bf16x8*)(Q + (bh384 + q0 + row) * 64 + cg);
  }
  __syncthreads();

  bf16x8 qf[2][2];
#pragma unroll
  for (int mf = 0; mf < 2; ++mf)
#pragma unroll
    for (int ks = 0; ks < 2; ++ks)
      qf[mf][ks] = *(const bf16x8*)(&u.Qs[wv * 32 + mf * 16 + lr][ks * 32 + lg * 8]);

  // --- T14: registers holding the NEXT chunk's K and VT tiles ------------
  const int krow = tid >> 3,  kcg = (tid & 7) * 8;    // K: rows 0..31 (+32i)
  const int vd   = tid >> 4,  vp  = (tid & 15) * 8;   // VT: d 0..15 (+16i)
  bf16x8 kreg[4], vreg[4];
  {
    size_t kb, vtb; chunk_base(0, kb, vtb);
#pragma unroll
    for (int i = 0; i < 4; ++i) {
      kreg[i] = *(const bf16x8*)(K + kb + (size_t)(krow + i * 32) * 64 + kcg);
      vreg[i] = *(const bf16x8*)(VT + vtb + (size_t)(vd + i * 16) * 384 + vp);
    }
  }

  f32x4 O[2][4] = {};
  float runmax[2] = {-1e30f, -1e30f}, runsum[2] = {0.f, 0.f};

  for (int c = 0; c < nchunks; ++c) {
    __syncthreads();   // previous chunk fully consumed before restaging
#pragma unroll
    for (int i = 0; i < 4; ++i) {
      *(bf16x8*)(&Ks[krow + i * 32][kcg]) = kreg[i];
      *(bf16x8*)(&VTs[vd + i * 16][vp])   = vreg[i];
    }
    __syncthreads();

    if (c + 1 < nchunks) {     // prefetch next chunk into regs (no wait here)
      size_t kb, vtb; chunk_base(c + 1, kb, vtb);
#pragma unroll
      for (int i = 0; i < 4; ++i) {
        kreg[i] = *(const bf16x8*)(K + kb + (size_t)(krow + i * 32) * 64 + kcg);
        vreg[i] = *(const bf16x8*)(VT + vtb + (size_t)(vd + i * 16) * 384 + vp);
      }
    }

    // St = K * Q^T (swapped): lane holds St[key = nf*16+lg*4+r][q = mf*16+lr]
    // (already in log2 domain: Q pre-scaled by 0.125*log2e)
    f32x4 St[2][8] = {};
#pragma unroll
    for (int nf = 0; nf < 8; ++nf) {
#pragma unroll
      for (int ks = 0; ks < 2; ++ks) {
        bf16x8 kf = *(const bf16x8*)(&Ks[nf * 16 + lr][ks * 32 + lg * 8]);
        St[0][nf] = MFMA16(kf, qf[0][ks], St[0][nf]);
        St[1][nf] = MFMA16(kf, qf[1][ks], St[1][nf]);
      }
    }

    // online softmax (exp2 domain), in-place, depth-5 trees, bare v_exp_f32
    float rfq[2];
#pragma unroll
    for (int mf = 0; mf < 2; ++mf) {
      float m4[8];
#pragma unroll
      for (int nf = 0; nf < 8; ++nf)
        m4[nf] = fmaxf(fmaxf(St[mf][nf][0], St[mf][nf][1]),
                       fmaxf(St[mf][nf][2], St[mf][nf][3]));
      float mx = fmaxf(fmaxf(fmaxf(m4[0], m4[1]), fmaxf(m4[2], m4[3])),
                       fmaxf(fmaxf(m4[4], m4[5]), fmaxf(m4[6], m4[7])));
      mx = fmaxf(mx, __shfl_xor(mx, 16));
      mx = fmaxf(mx, __shfl_xor(mx, 32));
      float nm = fmaxf(runmax[mf], mx);
      rfq[mf] = EXP2(runmax[mf] - nm);
      runmax[mf] = nm;
      float s4[8];
#pragma unroll
      for (int nf = 0; nf < 8; ++nf) {
        St[mf][nf][0] = EXP2(St[mf][nf][0] - nm);
        St[mf][nf][1] = EXP2(St[mf][nf][1] - nm);
        St[mf][nf][2] = EXP2(St[mf][nf][2] - nm);
        St[mf][nf][3] = EXP2(St[mf][nf][3] - nm);
        s4[nf] = (St[mf][nf][0] + St[mf][nf][1]) + (St[mf][nf][2] + St[mf][nf][3]);
      }
      float rs = ((s4[0] + s4[1]) + (s4[2] + s4[3])) +
                 ((s4[4] + s4[5]) + (s4[6] + s4[7]));
      rs += __shfl_xor(rs, 16);
      rs += __shfl_xor(rs, 32);
      runsum[mf] = runsum[mf] * rfq[mf] + rs;
    }

    // P write: lane holds 4 consecutive keys per (mf,nf) -> packed b64 store
#pragma unroll
    for (int mf = 0; mf < 2; ++mf)
#pragma unroll
      for (int nf = 0; nf < 8; ++nf) {
        bf16x4 pk;
        pk[0] = (bf16)St[mf][nf][0]; pk[1] = (bf16)St[mf][nf][1];
        pk[2] = (bf16)St[mf][nf][2]; pk[3] = (bf16)St[mf][nf][3];
        *(bf16x4*)(&u.Ps[wv][mf * 16 + lr][nf * 16 + lg * 4]) = pk;
      }

    // O rescale: O-row q' = mf*16 + lg*4 + r -> pull rf from lane lr'=lg*4+r
#pragma unroll
    for (int mf = 0; mf < 2; ++mf)
#pragma unroll
      for (int r = 0; r < 4; ++r) {
        float rr = __shfl(rfq[mf], (lg * 4 + r) + (lg << 4));
#pragma unroll
        for (int vn = 0; vn < 4; ++vn) O[mf][vn][r] *= rr;
      }

#pragma unroll
    for (int ks = 0; ks < 4; ++ks) {
      bf16x8 pf0 = *(const bf16x8*)(&u.Ps[wv][lr][ks * 32 + lg * 8]);
      bf16x8 pf1 = *(const bf16x8*)(&u.Ps[wv][16 + lr][ks * 32 + lg * 8]);
#pragma unroll
      for (int vn = 0; vn < 4; ++vn) {
        bf16x8 vf = *(const bf16x8*)(&VTs[vn * 16 + lr][ks * 32 + lg * 8]);
        O[0][vn] = MFMA16(pf0, vf, O[0][vn]);
        O[1][vn] = MFMA16(pf1, vf, O[1][vn]);
      }
    }
  }

  // epilogue: divide by runsum of O-row q' (pull from lane lr' = lg*4+r)
#pragma unroll
  for (int mf = 0; mf < 2; ++mf) {
#pragma unroll
    for (int r = 0; r < 4; ++r) {
      float rs = __shfl(runsum[mf], (lg * 4 + r) + (lg << 4));
      float inv = 1.0f / rs;
#pragma unroll
      for (int vn = 0; vn < 4; ++vn) {
        int tok = q0 + wv * 32 + mf * 16 + lg * 4 + r;
        int d = vn * 16 + lr;
        ATT[((size_t)bp * 384 + tok) * 768 + h * 64 + d] = (bf16)(O[mf][vn][r] * inv);
      }
    }
  }
}

// ---------------------------------------------------------------------------
// Kernel 3: output projection. 128x128 tile, BK=64, f32 out + bias.
// ---------------------------------------------------------------------------
__global__ __launch_bounds__(256, 2) void proj_kernel(
    const bf16* __restrict__ A, const bf16* __restrict__ W,
    const float* __restrict__ bias, float* __restrict__ out)
{
  __shared__ bf16 As[2][128][64];
  __shared__ bf16 Bs[2][128][64];
  int bid = blockIdx.x;                    // 1152 blocks
  int swz = (bid & 7) * 144 + (bid >> 3);  // 1152 = 8*144
  const int nt = swz % 6, mt = swz / 6;
  const int m0 = mt * 128, n0 = nt * 128;
  const int tid = threadIdx.x;
  const int lane = tid & 63;
  const int wv = tid >> 6;
  const int wr = (wv >> 1) * 64, wc = (wv & 1) * 64;
  const int lr = lane & 15, lg = lane >> 4;

  const bf16* Ap = A + (size_t)m0 * 768;
  const bf16* Wpp = W + (size_t)n0 * 768;

  f32x4 acc[4][4] = {};

  GEMM128_LOOP(Ap, Wpp, 12);

#pragma unroll
  for (int mf = 0; mf < 4; ++mf)
#pragma unroll
    for (int nf = 0; nf < 4; ++nf)
#pragma unroll
      for (int r = 0; r < 4; ++r) {
        int m = m0 + wr + mf * 16 + lg * 4 + r;
        int n = n0 + wc + nf * 16 + lr;
        out[(size_t)m * 768 + n] = acc[mf][nf][r] + bias[n];
      }
}

// ---------------------------------------------------------------------------
extern "C" void kernel_launch(void* const* d_in, const int* in_sizes, int n_in,
                              void* d_out, int out_size, void* d_ws, size_t ws_size,
                              hipStream_t stream) {
  (void)in_sizes; (void)n_in; (void)out_size; (void)ws_size;
  const float* xv     = (const float*)d_in[0];
  const float* xi     = (const float*)d_in[1];
  const float* qkv_w  = (const float*)d_in[2];
  const float* proj_w = (const float*)d_in[3];
  const float* proj_b = (const float*)d_in[4];
  float* out = (float*)d_out;

  // bf16 scratch inside d_out (75.5 MB): Xb [24576][768] then Wq [2304][768].
  bf16* Xb = (bf16*)d_out;
  bf16* Wq = Xb + (size_t)18874368;

  // ws: Q | K | VT | ATT, each 18874368 bf16 (~36 MB) = 151 MB total.
  const size_t SZ = (size_t)64 * 12 * 384 * 64;
  bf16* Q   = (bf16*)d_ws;
  bf16* K   = Q + SZ;
  bf16* VT  = K + SZ;
  bf16* ATT = VT + SZ;
  bf16* Wp  = Q;                 // proj_w bf16, reuses Q region after attn

  convert1_kernel<<<2048, 256, 0, stream>>>(xv, xi, qkv_w, Xb);
  qkv_kernel<<<3456, 256, 0, stream>>>(Xb, Wq, Q, K, VT);
  attn_kernel<<<64 * 12 * 3, 256, 0, stream>>>(Q, K, VT, ATT);
  convert2_kernel<<<288, 256, 0, stream>>>(proj_w, Wp);
  proj_kernel<<<1152, 256, 0, stream>>>(ATT, Wp, proj_b, out);
}

// Round 16
// 243.987 us; speedup vs baseline: 1.0831x; 1.0114x over previous
//
#include <hip/hip_runtime.h>

typedef __bf16 bf16;
typedef __bf16 bf16x4 __attribute__((ext_vector_type(4)));
typedef __bf16 bf16x8 __attribute__((ext_vector_type(8)));
typedef float f32x4 __attribute__((ext_vector_type(4)));

#define MFMA16(a,b,c) __builtin_amdgcn_mfma_f32_16x16x32_bf16((a),(b),(c),0,0,0)
#define SBAR() __builtin_amdgcn_s_barrier()
#define SCHED0() __builtin_amdgcn_sched_barrier(0)
#define EXP2(x) __builtin_amdgcn_exp2f(x)   // bare v_exp_f32 (= 2^x)

// Shapes (fixed): B=32, N=384, C=768, H=12, Dh=64, mt=128, 2B=64 batches.
// Global inputs/outputs FLOAT32; intermediates bf16.
// Xb (x bf16 [24576][768]) + Wq (qkv_w bf16 [2304][768]) live in d_out scratch.
// ws: Q | K | VT | ATT (each 36 MB bf16) = 151 MB; Wp reuses Q after attn.
// V stored TRANSPOSED (VT[b'][h][d][tok]) by the qkv epilogue.
//
// r16 (r15 best=246.8us): qkv epilogue LDS repack. Q/K blocks (whole block is
// one component since comp boundaries are 128-aligned) stage the 128x128 acc
// tile in LDS (ep[128][132]: 264B rows -> ds_write lanes tile 32 banks free)
// then store 16B/lane (8 stores/thread, full-line) instead of 64 scalar 2B
// stores -> kills L2 write-allocate RMW (~50MB excess FETCH) + 56 VMEM
// issues/thread. LDS unioned with As/Bs (dead after K-loop).

__device__ inline void gload16(const bf16* g, bf16* l) {
  __builtin_amdgcn_global_load_lds(
      (const __attribute__((address_space(1))) void*)g,
      (__attribute__((address_space(3))) void*)l, 16, 0, 0);
}

__device__ inline void stage128(const bf16* __restrict__ gsrc,
                                bf16* lds_base, int tid, int wv) {
#pragma unroll
  for (int r = 0; r < 4; ++r) {
    int s = r * 256 + tid;                        // 0..1023
    int row = s >> 3;
    int chunk = (s & 7) ^ (row & 7);
    gload16(gsrc + (size_t)row * 768 + chunk * 8,
            lds_base + (size_t)(r * 256 + wv * 64) * 8);
  }
}

__device__ inline bf16x8 frag64(const bf16* buf, int row, int ks, int lg) {
  int slot = ((ks << 2) | lg) ^ (row & 7);
  return *(const bf16x8*)(buf + (size_t)row * 64 + slot * 8);
}

// Counted-vmcnt K-loop over NTILES tiles of BK=64 (r8/r9, verified).
#define GEMM128_LOOP(APANEL, BPANEL, NTILES)                                    \
  do {                                                                          \
    stage128((APANEL), &As[0][0][0], tid, wv);                                  \
    stage128((BPANEL), &Bs[0][0][0], tid, wv);                                  \
    stage128((APANEL) + 64, &As[1][0][0], tid, wv);                             \
    stage128((BPANEL) + 64, &Bs[1][0][0], tid, wv);                             \
    asm volatile("s_waitcnt vmcnt(8)" ::: "memory"); SCHED0();                  \
    SBAR();                                                                     \
    int c = 0;                                                                  \
    for (int t = 0; t < (NTILES); ++t) {                                        \
      const bf16* Ab = &As[c][0][0];                                            \
      const bf16* Bb = &Bs[c][0][0];                                            \
      bf16x8 af[4][2], bfr[4][2];                                               \
      _Pragma("unroll")                                                         \
      for (int nf = 0; nf < 4; ++nf)                                            \
        _Pragma("unroll")                                                       \
        for (int ks = 0; ks < 2; ++ks)                                          \
          bfr[nf][ks] = frag64(Bb, wc + nf * 16 + lr, ks, lg);                  \
      _Pragma("unroll")                                                         \
      for (int mf = 0; mf < 4; ++mf)                                            \
        _Pragma("unroll")                                                       \
        for (int ks = 0; ks < 2; ++ks)                                          \
          af[mf][ks] = frag64(Ab, wr + mf * 16 + lr, ks, lg);                   \
      asm volatile("s_waitcnt lgkmcnt(0)" ::: "memory"); SCHED0();              \
      SBAR();   /* all waves done reading buf[c] -> safe to refill */           \
      if (t + 2 < (NTILES)) {                                                   \
        stage128((APANEL) + (t + 2) * 64, &As[c][0][0], tid, wv);               \
        stage128((BPANEL) + (t + 2) * 64, &Bs[c][0][0], tid, wv);               \
      }                                                                         \
      __builtin_amdgcn_s_setprio(1);                                            \
      _Pragma("unroll")                                                         \
      for (int mf = 0; mf < 4; ++mf)                                            \
        _Pragma("unroll")                                                       \
        for (int nf = 0; nf < 4; ++nf)                                          \
          _Pragma("unroll")                                                     \
          for (int ks = 0; ks < 2; ++ks)                                        \
            acc[mf][nf] = MFMA16(af[mf][ks], bfr[nf][ks], acc[mf][nf]);         \
      __builtin_amdgcn_s_setprio(0);                                            \
      if (t + 2 < (NTILES)) { asm volatile("s_waitcnt vmcnt(8)" ::: "memory"); }\
      else                  { asm volatile("s_waitcnt vmcnt(0)" ::: "memory"); }\
      SCHED0();                                                                 \
      SBAR();   /* buf[c^1] (tile t+1) now globally ready */                    \
      c ^= 1;                                                                   \
    }                                                                           \
  } while (0)

// ---------------------------------------------------------------------------
__global__ __launch_bounds__(256) void convert1_kernel(
    const float* __restrict__ xv, const float* __restrict__ xi,
    const float* __restrict__ w, bf16* __restrict__ dst)
{
  const size_t NV = 9437184;     // 12288*768
  const size_t NX = 18874368;    // 2*NV
  const size_t NT = 20643840;    // NX + 1769472 (qkv_w)
  for (size_t i = (size_t)blockIdx.x * 256 + threadIdx.x; i * 8 < NT;
       i += (size_t)gridDim.x * 256) {
    size_t e = i * 8;
    const float* src;
    if (e < NV)      src = xv + e;
    else if (e < NX) src = xi + (e - NV);
    else             src = w + (e - NX);
    f32x4 a = *(const f32x4*)src;
    f32x4 b = *(const f32x4*)(src + 4);
    bf16x8 r;
    r[0] = (bf16)a[0]; r[1] = (bf16)a[1]; r[2] = (bf16)a[2]; r[3] = (bf16)a[3];
    r[4] = (bf16)b[0]; r[5] = (bf16)b[1]; r[6] = (bf16)b[2]; r[7] = (bf16)b[3];
    *(bf16x8*)(dst + e) = r;
  }
}

__global__ __launch_bounds__(256) void convert2_kernel(
    const float* __restrict__ w, bf16* __restrict__ dst)
{
  size_t i = (size_t)blockIdx.x * 256 + threadIdx.x;
  size_t e = i * 8;
  if (e >= 589824) return;
  f32x4 a = *(const f32x4*)(w + e);
  f32x4 b = *(const f32x4*)(w + e + 4);
  bf16x8 r;
  r[0] = (bf16)a[0]; r[1] = (bf16)a[1]; r[2] = (bf16)a[2]; r[3] = (bf16)a[3];
  r[4] = (bf16)b[0]; r[5] = (bf16)b[1]; r[6] = (bf16)b[2]; r[7] = (bf16)b[3];
  *(bf16x8*)(dst + e) = r;
}

// ---------------------------------------------------------------------------
// Kernel 1: QKV projection. 128x128 tile, BK=64. Epilogue: V transposed
// (bf16x4), Q/K repacked via LDS and stored 16B/lane. Q scaled 0.125*log2e.
// ---------------------------------------------------------------------------
__global__ __launch_bounds__(256, 2) void qkv_kernel(
    const bf16* __restrict__ X, const bf16* __restrict__ W,
    bf16* __restrict__ Qo, bf16* __restrict__ Ko, bf16* __restrict__ VTo)
{
  __shared__ union {
    struct { bf16 A[2][128][64]; bf16 B[2][128][64]; } k;
    bf16 ep[128][132];                 // 264B rows: epilogue repack tile
  } lds;
  bf16 (&As)[2][128][64] = lds.k.A;
  bf16 (&Bs)[2][128][64] = lds.k.B;

  int bid = blockIdx.x;                    // 3456 blocks
  int swz = (bid & 7) * 432 + (bid >> 3);  // XCD-contiguous, bijective
  const int nt = swz % 18, mt = swz / 18;
  const int m0 = mt * 128, n0 = nt * 128;
  const int tid = threadIdx.x;
  const int lane = tid & 63;
  const int wv = tid >> 6;                 // 0..3
  const int wr = (wv >> 1) * 64, wc = (wv & 1) * 64;
  const int lr = lane & 15, lg = lane >> 4;

  const bf16* Xp = X + (size_t)m0 * 768;
  const bf16* Wp = W + (size_t)n0 * 768;

  f32x4 acc[4][4] = {};

  GEMM128_LOOP(Xp, Wp, 12);

  const int comp = nt / 6;                 // block-uniform: 0=Q 1=K 2=V
  if (comp == 2) {
#pragma unroll
    for (int mf = 0; mf < 4; ++mf)
#pragma unroll
      for (int nf = 0; nf < 4; ++nf) {
        int m = m0 + wr + mf * 16 + lg * 4;       // 4-aligned token base
        int n = n0 + wc + nf * 16 + lr;
        int bp = m / 384, tok = m - bp * 384;
        int rem = n - 1536;
        int hh = rem >> 6, d = rem & 63;
        bf16x4 pk;
        pk[0] = (bf16)acc[mf][nf][0]; pk[1] = (bf16)acc[mf][nf][1];
        pk[2] = (bf16)acc[mf][nf][2]; pk[3] = (bf16)acc[mf][nf][3];
        *(bf16x4*)(VTo + (((size_t)bp * 12 + hh) * 64 + d) * 384 + tok) = pk;
      }
  } else {
    const float scl = (comp == 0) ? 0.18033688f : 1.0f;  // Q: 0.125*log2(e)
    // acc -> LDS (ds_write lanes tile 32 banks: lg stride=8 banks, lr span=8)
#pragma unroll
    for (int mf = 0; mf < 4; ++mf)
#pragma unroll
      for (int nf = 0; nf < 4; ++nf)
#pragma unroll
        for (int r = 0; r < 4; ++r)
          lds.ep[wr + mf * 16 + lg * 4 + r][wc + nf * 16 + lr] =
              (bf16)(acc[mf][nf][r] * scl);
    __syncthreads();
    bf16* dst = (comp == 0) ? Qo : Ko;
    const int nb = n0 - comp * 768;
#pragma unroll
    for (int it = 0; it < 8; ++it) {
      int idx = it * 256 + tid;            // 0..2047 = 128 rows x 16 chunks
      int row = idx >> 4, ch = idx & 15;
      int m = m0 + row;
      int bp = m / 384, tok = m - bp * 384;
      int rem = nb + ch * 8;               // 8-elem chunk, never crosses d=64
      int hh = rem >> 6, d = rem & 63;
      *(bf16x8*)(dst + (((size_t)bp * 12 + hh) * 384 + tok) * 64 + d) =
          *(const bf16x8*)(&lds.ep[row][ch * 8]);
    }
  }
}

// ---------------------------------------------------------------------------
// Kernel 2: attention, swapped-QK^T lane-local softmax (v_exp_f32 direct,
// in-place depth-5 reduce) + T14 reg-prefetch. grid = 64*12*3.
// ---------------------------------------------------------------------------
__global__ __launch_bounds__(256) void attn_kernel(
    const bf16* __restrict__ Q, const bf16* __restrict__ K, const bf16* __restrict__ VT,
    bf16* __restrict__ ATT)
{
  __shared__ union {
    bf16 Qs[128][72];
    bf16 Ps[4][32][136];     // per-wave P tile [q_local][key] (Qs dead after qf cache)
  } u;
  __shared__ bf16 Ks[128][72];
  __shared__ bf16 VTs[64][136];     // transposed V: [d][token]

  const int bid = blockIdx.x;
  const int qb = bid % 3;
  const int h  = (bid / 3) % 12;
  const int bp = bid / 36;           // b' in [0,64)
  const int tid = threadIdx.x;
  const int lane = tid & 63;
  const int wv = tid >> 6;
  const int lr = lane & 15, lg = lane >> 4;

  const size_t bh384 = ((size_t)bp * 12 + h) * 384;
  const int q0 = qb * 128;
  const int nchunks = (qb == 0) ? 1 : 4;

  // chunk -> (src_b, t0)
  auto chunk_base = [&](int c, size_t& kb, size_t& vtb) {
    int src_b, t0;
    if (qb == 0)      { src_b = bp;             t0 = 0; }
    else if (c == 0)  { src_b = bp & 31;        t0 = 0; }
    else if (c == 1)  { src_b = (bp & 31) + 32; t0 = 0; }
    else              { src_b = bp;             t0 = (c - 1) * 128; }
    kb  = (((size_t)src_b * 12 + h) * 384 + t0) * 64;
    vtb = ((size_t)src_b * 12 + h) * 64 * 384 + t0;
  };

  for (int v = tid; v < 1024; v += 256) {
    int row = v >> 3, cg = (v & 7) * 8;
    *(bf16x8*)(&u.Qs[row][cg]) = *(const bf16x8*)(Q + (bh384 + q0 + row) * 64 + cg);
  }
  __syncthreads();

  bf16x8 qf[2][2];
#pragma unroll
  for (int mf = 0; mf < 2; ++mf)
#pragma unroll
    for (int ks = 0; ks < 2; ++ks)
      qf[mf][ks] = *(const bf16x8*)(&u.Qs[wv * 32 + mf * 16 + lr][ks * 32 + lg * 8]);

  // --- T14: registers holding the NEXT chunk's K and VT tiles ------------
  const int krow = tid >> 3,  kcg = (tid & 7) * 8;    // K: rows 0..31 (+32i)
  const int vd   = tid >> 4,  vp  = (tid & 15) * 8;   // VT: d 0..15 (+16i)
  bf16x8 kreg[4], vreg[4];
  {
    size_t kb, vtb; chunk_base(0, kb, vtb);
#pragma unroll
    for (int i = 0; i < 4; ++i) {
      kreg[i] = *(const bf16x8*)(K + kb + (size_t)(krow + i * 32) * 64 + kcg);
      vreg[i] = *(const bf16x8*)(VT + vtb + (size_t)(vd + i * 16) * 384 + vp);
    }
  }

  f32x4 O[2][4] = {};
  float runmax[2] = {-1e30f, -1e30f}, runsum[2] = {0.f, 0.f};

  for (int c = 0; c < nchunks; ++c) {
    __syncthreads();   // previous chunk fully consumed before restaging
#pragma unroll
    for (int i = 0; i < 4; ++i) {
      *(bf16x8*)(&Ks[krow + i * 32][kcg]) = kreg[i];
      *(bf16x8*)(&VTs[vd + i * 16][vp])   = vreg[i];
    }
    __syncthreads();

    if (c + 1 < nchunks) {     // prefetch next chunk into regs (no wait here)
      size_t kb, vtb; chunk_base(c + 1, kb, vtb);
#pragma unroll
      for (int i = 0; i < 4; ++i) {
        kreg[i] = *(const bf16x8*)(K + kb + (size_t)(krow + i * 32) * 64 + kcg);
        vreg[i] = *(const bf16x8*)(VT + vtb + (size_t)(vd + i * 16) * 384 + vp);
      }
    }

    // St = K * Q^T (swapped): lane holds St[key = nf*16+lg*4+r][q = mf*16+lr]
    // (already in log2 domain: Q pre-scaled by 0.125*log2e)
    f32x4 St[2][8] = {};
#pragma unroll
    for (int nf = 0; nf < 8; ++nf) {
#pragma unroll
      for (int ks = 0; ks < 2; ++ks) {
        bf16x8 kf = *(const bf16x8*)(&Ks[nf * 16 + lr][ks * 32 + lg * 8]);
        St[0][nf] = MFMA16(kf, qf[0][ks], St[0][nf]);
        St[1][nf] = MFMA16(kf, qf[1][ks], St[1][nf]);
      }
    }

    // online softmax (exp2 domain), in-place, depth-5 trees, bare v_exp_f32
    float rfq[2];
#pragma unroll
    for (int mf = 0; mf < 2; ++mf) {
      float m4[8];
#pragma unroll
      for (int nf = 0; nf < 8; ++nf)
        m4[nf] = fmaxf(fmaxf(St[mf][nf][0], St[mf][nf][1]),
                       fmaxf(St[mf][nf][2], St[mf][nf][3]));
      float mx = fmaxf(fmaxf(fmaxf(m4[0], m4[1]), fmaxf(m4[2], m4[3])),
                       fmaxf(fmaxf(m4[4], m4[5]), fmaxf(m4[6], m4[7])));
      mx = fmaxf(mx, __shfl_xor(mx, 16));
      mx = fmaxf(mx, __shfl_xor(mx, 32));
      float nm = fmaxf(runmax[mf], mx);
      rfq[mf] = EXP2(runmax[mf] - nm);
      runmax[mf] = nm;
      float s4[8];
#pragma unroll
      for (int nf = 0; nf < 8; ++nf) {
        St[mf][nf][0] = EXP2(St[mf][nf][0] - nm);
        St[mf][nf][1] = EXP2(St[mf][nf][1] - nm);
        St[mf][nf][2] = EXP2(St[mf][nf][2] - nm);
        St[mf][nf][3] = EXP2(St[mf][nf][3] - nm);
        s4[nf] = (St[mf][nf][0] + St[mf][nf][1]) + (St[mf][nf][2] + St[mf][nf][3]);
      }
      float rs = ((s4[0] + s4[1]) + (s4[2] + s4[3])) +
                 ((s4[4] + s4[5]) + (s4[6] + s4[7]));
      rs += __shfl_xor(rs, 16);
      rs += __shfl_xor(rs, 32);
      runsum[mf] = runsum[mf] * rfq[mf] + rs;
    }

    // P write: lane holds 4 consecutive keys per (mf,nf) -> packed b64 store
#pragma unroll
    for (int mf = 0; mf < 2; ++mf)
#pragma unroll
      for (int nf = 0; nf < 8; ++nf) {
        bf16x4 pk;
        pk[0] = (bf16)St[mf][nf][0]; pk[1] = (bf16)St[mf][nf][1];
        pk[2] = (bf16)St[mf][nf][2]; pk[3] = (bf16)St[mf][nf][3];
        *(bf16x4*)(&u.Ps[wv][mf * 16 + lr][nf * 16 + lg * 4]) = pk;
      }

    // O rescale: O-row q' = mf*16 + lg*4 + r -> pull rf from lane lr'=lg*4+r
#pragma unroll
    for (int mf = 0; mf < 2; ++mf)
#pragma unroll
      for (int r = 0; r < 4; ++r) {
        float rr = __shfl(rfq[mf], (lg * 4 + r) + (lg << 4));
#pragma unroll
        for (int vn = 0; vn < 4; ++vn) O[mf][vn][r] *= rr;
      }

#pragma unroll
    for (int ks = 0; ks < 4; ++ks) {
      bf16x8 pf0 = *(const bf16x8*)(&u.Ps[wv][lr][ks * 32 + lg * 8]);
      bf16x8 pf1 = *(const bf16x8*)(&u.Ps[wv][16 + lr][ks * 32 + lg * 8]);
#pragma unroll
      for (int vn = 0; vn < 4; ++vn) {
        bf16x8 vf = *(const bf16x8*)(&VTs[vn * 16 + lr][ks * 32 + lg * 8]);
        O[0][vn] = MFMA16(pf0, vf, O[0][vn]);
        O[1][vn] = MFMA16(pf1, vf, O[1][vn]);
      }
    }
  }

  // epilogue: divide by runsum of O-row q' (pull from lane lr' = lg*4+r)
#pragma unroll
  for (int mf = 0; mf < 2; ++mf) {
#pragma unroll
    for (int r = 0; r < 4; ++r) {
      float rs = __shfl(runsum[mf], (lg * 4 + r) + (lg << 4));
      float inv = 1.0f / rs;
#pragma unroll
      for (int vn = 0; vn < 4; ++vn) {
        int tok = q0 + wv * 32 + mf * 16 + lg * 4 + r;
        int d = vn * 16 + lr;
        ATT[((size_t)bp * 384 + tok) * 768 + h * 64 + d] = (bf16)(O[mf][vn][r] * inv);
      }
    }
  }
}

// ---------------------------------------------------------------------------
// Kernel 3: output projection. 128x128 tile, BK=64, f32 out + bias.
// ---------------------------------------------------------------------------
__global__ __launch_bounds__(256, 2) void proj_kernel(
    const bf16* __restrict__ A, const bf16* __restrict__ W,
    const float* __restrict__ bias, float* __restrict__ out)
{
  __shared__ bf16 As[2][128][64];
  __shared__ bf16 Bs[2][128][64];
  int bid = blockIdx.x;                    // 1152 blocks
  int swz = (bid & 7) * 144 + (bid >> 3);  // 1152 = 8*144
  const int nt = swz % 6, mt = swz / 6;
  const int m0 = mt * 128, n0 = nt * 128;
  const int tid = threadIdx.x;
  const int lane = tid & 63;
  const int wv = tid >> 6;
  const int wr = (wv >> 1) * 64, wc = (wv & 1) * 64;
  const int lr = lane & 15, lg = lane >> 4;

  const bf16* Ap = A + (size_t)m0 * 768;
  const bf16* Wpp = W + (size_t)n0 * 768;

  f32x4 acc[4][4] = {};

  GEMM128_LOOP(Ap, Wpp, 12);

#pragma unroll
  for (int mf = 0; mf < 4; ++mf)
#pragma unroll
    for (int nf = 0; nf < 4; ++nf)
#pragma unroll
      for (int r = 0; r < 4; ++r) {
        int m = m0 + wr + mf * 16 + lg * 4 + r;
        int n = n0 + wc + nf * 16 + lr;
        out[(size_t)m * 768 + n] = acc[mf][nf][r] + bias[n];
      }
}

// ---------------------------------------------------------------------------
extern "C" void kernel_launch(void* const* d_in, const int* in_sizes, int n_in,
                              void* d_out, int out_size, void* d_ws, size_t ws_size,
                              hipStream_t stream) {
  (void)in_sizes; (void)n_in; (void)out_size; (void)ws_size;
  const float* xv     = (const float*)d_in[0];
  const float* xi     = (const float*)d_in[1];
  const float* qkv_w  = (const float*)d_in[2];
  const float* proj_w = (const float*)d_in[3];
  const float* proj_b = (const float*)d_in[4];
  float* out = (float*)d_out;

  // bf16 scratch inside d_out (75.5 MB): Xb [24576][768] then Wq [2304][768].
  bf16* Xb = (bf16*)d_out;
  bf16* Wq = Xb + (size_t)18874368;

  // ws: Q | K | VT | ATT, each 18874368 bf16 (~36 MB) = 151 MB total.
  const size_t SZ = (size_t)64 * 12 * 384 * 64;
  bf16* Q   = (bf16*)d_ws;
  bf16* K   = Q + SZ;
  bf16* VT  = K + SZ;
  bf16* ATT = VT + SZ;
  bf16* Wp  = Q;                 // proj_w bf16, reuses Q region after attn

  convert1_kernel<<<2048, 256, 0, stream>>>(xv, xi, qkv_w, Xb);
  qkv_kernel<<<3456, 256, 0, stream>>>(Xb, Wq, Q, K, VT);
  attn_kernel<<<64 * 12 * 3, 256, 0, stream>>>(Q, K, VT, ATT);
  convert2_kernel<<<288, 256, 0, stream>>>(proj_w, Wp);
  proj_kernel<<<1152, 256, 0, stream>>>(ATT, Wp, proj_b, out);
}